// Round 20
// baseline (82.823 us; speedup 1.0000x reference)
//
#include <hip/hip_runtime.h>
#include <hip/hip_bf16.h>

#define NN 262144
#define DD 32
#define HH 31
#define KK 21
#define ROWS 256                 // rows per block (2 half-row chunks per thread)
#define FSTRIDE 20               // u32 words per feats row (80 B, 16B-aligned)
#define CSTRIDE 68               // floats per k in const table {b1'[32],w2[32],b2,pad3}
#define MAXT 40                  // max tiles per block (<= 16 + 21)

typedef __attribute__((ext_vector_type(8))) short bf16x8;
typedef __attribute__((ext_vector_type(4))) float f32x4;
typedef __attribute__((ext_vector_type(2))) unsigned int u32x2;
typedef __attribute__((ext_vector_type(4))) unsigned int u32x4;

static __device__ __forceinline__ unsigned short f2bf(float f) {
    __hip_bfloat16 h = __float2bfloat16(f);      // round-to-nearest-even
    return __builtin_bit_cast(unsigned short, h);
}
// single-instruction packed f32->bf16 (RNE), lo -> bits[15:0]
static __device__ __forceinline__ unsigned cvtpk(float lo, float hi) {
    unsigned r;
    asm("v_cvt_pk_bf16_f32 %0, %1, %2" : "=v"(r) : "v"(lo), "v"(hi));
    return r;
}

// ---------------- Fused single dispatch ----------------
// Blocks 0..20 additionally produce the k-tables (A-fragments of a*W1^T,
// b1' = b1 + b.W1, w2, b2) before their own phase 1, then release `flag`.
// All blocks consume tables only in phase 3, gated by a spin on flag==21.
// Grid (1024) <= resident capacity (>=4 blocks/CU by LDS/VGPR) -> no deadlock.
__global__ __launch_bounds__(256, 4) void fused_kernel(
    const float* __restrict__ x,
    const float* __restrict__ W1, const float* __restrict__ b1,
    const float* __restrict__ W2, const float* __restrict__ b2,
    const float* __restrict__ av, const float* __restrict__ bv,
    bf16x8* __restrict__ A0tab, bf16x8* __restrict__ A1tab,
    float* __restrict__ gcst,
    int* __restrict__ flagp,
    float* __restrict__ out)
{
    __shared__ __align__(16) unsigned fbf[ROWS * FSTRIDE];    // 20480 B
    __shared__ __align__(16) float scst[KK * CSTRIDE];        // 5712 B
    __shared__ float sedges[KK + 1];
    __shared__ int cnt[KK];
    __shared__ int rnk[KK];
    __shared__ int sbase[KK];
    __shared__ int tstart[KK + 1];
    __shared__ int tilek[MAXT];
    __shared__ unsigned short sorted[ROWS];

    const int tid = (int)threadIdx.x;
    const int lane = tid & 63;
    const int wave = tid >> 6;
    const int rowbase = (int)blockIdx.x * ROWS;

    // ---- Producer role: blocks 0..20 build tables for k = blockIdx.x ----
    if (blockIdx.x < KK) {
        const int k = (int)blockIdx.x;
        const float* __restrict__ W1k = W1 + k * HH * HH;
        if (tid < 64) {
            const int lrow = tid & 15, lgrp = tid >> 4;
            const int e0 = lrow, e1 = 16 + lrow;
            bf16x8 A0, A1;
            #pragma unroll
            for (int j = 0; j < 4; ++j) {
                const int d1 = 4 * lgrp + j;
                const int d2 = 16 + 4 * lgrp + j;
                A0[j]     = (short)f2bf(av[d1] * W1k[d1 * HH + e0]);
                A0[4 + j] = (d2 < HH) ? (short)f2bf(av[d2] * W1k[d2 * HH + e0]) : (short)0;
                A1[j]     = (e1 < HH) ? (short)f2bf(av[d1] * W1k[d1 * HH + e1]) : (short)0;
                A1[4 + j] = (e1 < HH && d2 < HH) ? (short)f2bf(av[d2] * W1k[d2 * HH + e1]) : (short)0;
            }
            A0tab[k * 64 + tid] = A0;
            A1tab[k * 64 + tid] = A1;

            for (int i = tid; i < CSTRIDE; i += 64) {
                float v = 0.0f;
                if (i < 32) {
                    if (i < HH) {
                        float s = b1[k * HH + i];
                        for (int d = 0; d < HH; ++d) s = fmaf(bv[d], W1k[d * HH + i], s);
                        v = s;
                    }
                } else if (i < 64) {
                    const int e = i - 32; if (e < HH) v = W2[k * HH + e];
                } else if (i == 64) v = b2[k];
                gcst[k * CSTRIDE + i] = v;
            }
        }
        __syncthreads();                 // all producer stores issued+drained
        if (tid == 0) {
            __threadfence();             // release: L2 writeback (device scope)
            atomicAdd(flagp, 1);
        }
    }

    if (tid < KK) { cnt[tid] = 0; rnk[tid] = 0; }
    if (tid < KK + 1)
        sedges[tid] = (tid == KK) ? 1000.0f : (float)tid / 10.0f;  // IEEE j/10
    __syncthreads();                                          // BAR1

    // ---- Phase 1: pack raw x (bf16) into LDS; arithmetic bucket ----
    int kq[2] = {-1, -1};
    #pragma unroll
    for (int i = 0; i < 2; ++i) {
        const int c    = tid + 256 * i;
        const int row  = c >> 1;
        const int half = c & 1;
        const float4* __restrict__ p =
            reinterpret_cast<const float4*>(x) + (size_t)blockIdx.x * (ROWS * DD / 4) + c * 4;
        float4 cc[4];
        #pragma unroll
        for (int j = 0; j < 4; ++j) cc[j] = p[j];

        const float e16 = __shfl(cc[0].x, lane + 1);  // odd lane's elem0 = x[16]
        const float t = cc[0].x;

        if (half == 0) {
            // candidate = ceil(t*10)-1, verified +-1 against exact edges
            int kc = (int)ceilf(t * 10.0f) - 1;
            kc = (kc < 0) ? 0 : ((kc > 19) ? 19 : kc);
            const float elo = sedges[kc];
            const float ehi = sedges[kc + 1];
            int kk = kc;
            if (t <= elo) kk = kc - 1;
            else if (t > ehi) kk = kc + 1;
            if (t > 2.0f) kk = (t <= 1000.0f) ? 20 : -1;
            if (t <= 0.0f) kk = -1;
            kq[i] = kk;
            if (kk >= 0) atomicAdd(&cnt[kk], 1);
            else out[rowbase + row] = 0.0f;
        }

        // even: x[1..16] (e16 via shfl); odd: x[17..31], pad 0
        const float* cf = (const float*)cc;
        const float f15 = half ? 0.0f : e16;
        unsigned* __restrict__ frow = fbf + row * FSTRIDE + half * 8;
        u32x4 w0, w1;
        w0[0] = cvtpk(cf[1], cf[2]);
        w0[1] = cvtpk(cf[3], cf[4]);
        w0[2] = cvtpk(cf[5], cf[6]);
        w0[3] = cvtpk(cf[7], cf[8]);
        w1[0] = cvtpk(cf[9], cf[10]);
        w1[1] = cvtpk(cf[11], cf[12]);
        w1[2] = cvtpk(cf[13], cf[14]);
        w1[3] = cvtpk(cf[15], f15);
        ((u32x4*)frow)[0] = w0;          // 2x ds_write_b128
        ((u32x4*)frow)[1] = w1;
    }
    __syncthreads();                                          // BAR2

    // ---- Phase 2: wave-parallel scan + tile->k table + scatter ----
    if (tid < 64) {
        const int j = tid;
        const int c0 = (j < KK) ? cnt[j] : 0;
        const int t0 = (j < KK) ? ((c0 + 15) >> 4) : 0;
        int sc = c0, st = t0;
        #pragma unroll
        for (int off = 1; off < 32; off <<= 1) {
            const int vc = __shfl_up(sc, off);
            const int vt = __shfl_up(st, off);
            if (j >= off) { sc += vc; st += vt; }
        }
        if (j < KK) {
            sbase[j] = sc - c0;
            tstart[j] = st - t0;
            for (int t = st - t0; t < st; ++t) tilek[t] = j;   // tile -> bucket
        }
        if (j == KK) tstart[KK] = st;
    }
    __syncthreads();                                          // BAR3
    #pragma unroll
    for (int i = 0; i < 2; ++i) {
        const int c = tid + 256 * i;
        if (!(c & 1) && kq[i] >= 0) {
            const int rr = atomicAdd(&rnk[kq[i]], 1);
            sorted[sbase[kq[i]] + rr] = (unsigned short)(c >> 1);
        }
    }
    __syncthreads();                                          // BAR4

    // ---- Gate: wait for all 21 producers, acquire, stage const table ----
    if (tid == 0) {
        while (__hip_atomic_load(flagp, __ATOMIC_RELAXED, __HIP_MEMORY_SCOPE_AGENT) < KK)
            __builtin_amdgcn_s_sleep(2);
    }
    __syncthreads();
    __threadfence();                     // acquire: invalidate L1
    for (int i = tid; i < KK * CSTRIDE / 4; i += 256)
        ((f32x4*)scst)[i] = ((const f32x4*)gcst)[i];
    __syncthreads();                                          // BAR5

    // ---- Phase 3: software-pipelined MFMA tiles (bias as MFMA C-init) ----
    const int lrow = lane & 15;
    const int lgrp = lane >> 4;
    const int NT = tstart[KK];

    int tix = wave;
    int k0 = 0, cn0 = 0, rl0 = 0, R0 = 0;
    bf16x8 A0c = {}, A1c = {}, Bc = {};

    if (tix < NT) {
        k0 = __builtin_amdgcn_readfirstlane(tilek[tix]);
        cn0 = cnt[k0];
        rl0 = (tix - tstart[k0]) * 16 + lrow;
        R0 = sorted[sbase[k0] + min(rl0, cn0 - 1)];
        const unsigned* __restrict__ fr = fbf + R0 * FSTRIDE;
        const u32x2 wlo = *(const u32x2*)(fr + 2 * lgrp);
        const u32x2 whi = *(const u32x2*)(fr + 8 + 2 * lgrp);
        u32x4 bw; bw[0] = wlo[0]; bw[1] = wlo[1]; bw[2] = whi[0]; bw[3] = whi[1];
        Bc = __builtin_bit_cast(bf16x8, bw);
        A0c = A0tab[k0 * 64 + lane];
        A1c = A1tab[k0 * 64 + lane];
    }

    while (tix < NT) {
        const int nxt = tix + 4;
        const int pt = (nxt < NT) ? nxt : tix;
        const int k1 = __builtin_amdgcn_readfirstlane(tilek[pt]);
        const int cn1 = cnt[k1];
        const int rl1 = (pt - tstart[k1]) * 16 + lrow;
        const int R1 = sorted[sbase[k1] + min(rl1, cn1 - 1)];
        const unsigned* __restrict__ frn = fbf + R1 * FSTRIDE;
        const u32x2 nlo = *(const u32x2*)(frn + 2 * lgrp);
        const u32x2 nhi = *(const u32x2*)(frn + 8 + 2 * lgrp);
        u32x4 nw; nw[0] = nlo[0]; nw[1] = nlo[1]; nw[2] = nhi[0]; nw[3] = nhi[1];
        const bf16x8 Bn = __builtin_bit_cast(bf16x8, nw);
        const bf16x8 A0n = A0tab[k1 * 64 + lane];
        const bf16x8 A1n = A1tab[k1 * 64 + lane];

        const float* __restrict__ cp = scst + k0 * CSTRIDE;
        const f32x4 cb0 = *(const f32x4*)(cp + 4 * lgrp);
        const f32x4 cb1 = *(const f32x4*)(cp + 16 + 4 * lgrp);
        const f32x4 cw0 = *(const f32x4*)(cp + 32 + 4 * lgrp);
        const f32x4 cw1 = *(const f32x4*)(cp + 48 + 4 * lgrp);
        const float b2k = cp[64];

        // bias rides in as the MFMA C operand: h = b1' + A*B
        f32x4 acc0 = __builtin_amdgcn_mfma_f32_16x16x32_bf16(A0c, Bc, cb0, 0, 0, 0);
        f32x4 acc1 = __builtin_amdgcn_mfma_f32_16x16x32_bf16(A1c, Bc, cb1, 0, 0, 0);

        float S = 0.0f;
        #pragma unroll
        for (int rr = 0; rr < 4; ++rr) {
            const float q0 = fmaxf(acc0[rr], 0.1f * acc0[rr]);   // lrelu
            S = fmaf(q0, cw0[rr], S);
            const float q1 = fmaxf(acc1[rr], 0.1f * acc1[rr]);
            S = fmaf(q1, cw1[rr], S);
        }
        S += __shfl_xor(S, 16);
        S += __shfl_xor(S, 32);

        if (lgrp == 0 && rl0 < cn0) out[rowbase + R0] = S + b2k;

        k0 = k1; cn0 = cn1; rl0 = rl1; R0 = R1;
        A0c = A0n; A1c = A1n; Bc = Bn;
        tix = nxt;
    }
}

extern "C" void kernel_launch(void* const* d_in, const int* in_sizes, int n_in,
                              void* d_out, int out_size, void* d_ws, size_t ws_size,
                              hipStream_t stream) {
    const float* x  = (const float*)d_in[0];
    const float* a  = (const float*)d_in[1];
    const float* b  = (const float*)d_in[2];
    const float* W1 = (const float*)d_in[3];
    const float* b1 = (const float*)d_in[4];
    const float* W2 = (const float*)d_in[5];
    const float* b2 = (const float*)d_in[6];
    float* out = (float*)d_out;

    char* ws = (char*)d_ws;
    int* flagp = (int*)ws;                             // 64 B reserved
    bf16x8* A0tab = (bf16x8*)(ws + 64);                // 21*64*16B
    bf16x8* A1tab = A0tab + KK * 64;                   // 21*64*16B
    float* gcst  = (float*)(A1tab + KK * 64);          // 21*68*4B

    hipMemsetAsync(flagp, 0, sizeof(int), stream);

    hipLaunchKernelGGL(fused_kernel, dim3(NN / ROWS), dim3(256), 0, stream,
                       x, W1, b1, W2, b2, a, b, A0tab, A1tab, gcst, flagp, out);
}

// Round 21
// 19.609 us; speedup vs baseline: 4.2238x; 4.2238x over previous
//
#include <hip/hip_runtime.h>
#include <hip/hip_bf16.h>

#define NN 262144
#define DD 32
#define HH 31
#define KK 21
#define ROWS 256                 // rows per block (2 half-row chunks per thread)
#define FSTRIDE 18               // u32 words per feats row (72 B)
#define CSTRIDE 68               // floats per k in const table {b1'[32],w2[32],b2,pad3}
#define MAXT 40                  // max tiles per block (<= 16 + 21)

typedef __attribute__((ext_vector_type(8))) short bf16x8;
typedef __attribute__((ext_vector_type(4))) float f32x4;
typedef __attribute__((ext_vector_type(2))) unsigned int u32x2;
typedef __attribute__((ext_vector_type(4))) unsigned int u32x4;

static __device__ __forceinline__ unsigned short f2bf(float f) {
    __hip_bfloat16 h = __float2bfloat16(f);      // round-to-nearest-even
    return __builtin_bit_cast(unsigned short, h);
}
// single-instruction packed f32->bf16 (RNE), lo -> bits[15:0]
static __device__ __forceinline__ unsigned cvtpk(float lo, float hi) {
    unsigned r;
    asm("v_cvt_pk_bf16_f32 %0, %1, %2" : "=v"(r) : "v"(lo), "v"(hi));
    return r;
}

// ---------------- Prep: fold a,b into weights; build tables ----------------
// A0/A1tab[k][lane]: bf16( a[d] * W1[k][d][e] )  (A = scaled W1^T fragments)
// gcst[k]: { b1'[32] = b1 + sum_d b[d]*W1[d][e], w2[32], b2, pad }
__global__ __launch_bounds__(64) void prep_kernel(
    const float* __restrict__ W1, const float* __restrict__ b1,
    const float* __restrict__ W2, const float* __restrict__ b2,
    const float* __restrict__ av, const float* __restrict__ bv,
    bf16x8* __restrict__ A0tab, bf16x8* __restrict__ A1tab,
    float* __restrict__ gcst)
{
    const int k = (int)blockIdx.x;
    const int lane = (int)threadIdx.x;
    const int lrow = lane & 15, lgrp = lane >> 4;
    const float* __restrict__ W1k = W1 + k * HH * HH;
    const int e0 = lrow, e1 = 16 + lrow;

    bf16x8 A0, A1;
    #pragma unroll
    for (int j = 0; j < 4; ++j) {
        const int d1 = 4 * lgrp + j;
        const int d2 = 16 + 4 * lgrp + j;
        A0[j]     = (short)f2bf(av[d1] * W1k[d1 * HH + e0]);
        A0[4 + j] = (d2 < HH) ? (short)f2bf(av[d2] * W1k[d2 * HH + e0]) : (short)0;
        A1[j]     = (e1 < HH) ? (short)f2bf(av[d1] * W1k[d1 * HH + e1]) : (short)0;
        A1[4 + j] = (e1 < HH && d2 < HH) ? (short)f2bf(av[d2] * W1k[d2 * HH + e1]) : (short)0;
    }
    A0tab[k * 64 + lane] = A0;
    A1tab[k * 64 + lane] = A1;

    for (int i = lane; i < CSTRIDE; i += 64) {
        float v = 0.0f;
        if (i < 32) {
            if (i < HH) {
                float s = b1[k * HH + i];
                for (int d = 0; d < HH; ++d) s = fmaf(bv[d], W1k[d * HH + i], s);
                v = s;
            }
        } else if (i < 64) {
            const int e = i - 32; if (e < HH) v = W2[k * HH + e];
        } else if (i == 64) v = b2[k];
        gcst[k * CSTRIDE + i] = v;
    }
}

// ---------------- Fused: sort + software-pipelined MFMA ----------------
__global__ __launch_bounds__(256, 4) void fused_kernel(
    const float* __restrict__ x,
    const bf16x8* __restrict__ A0tab, const bf16x8* __restrict__ A1tab,
    const float* __restrict__ gcst,
    float* __restrict__ out)
{
    __shared__ unsigned fbf[ROWS * FSTRIDE];                  // 18432 B
    __shared__ __align__(16) float scst[KK * CSTRIDE];        // 5712 B
    __shared__ float sedges[KK + 1];
    __shared__ int cnt[KK];
    __shared__ int rnk[KK];
    __shared__ int sbase[KK];
    __shared__ int tstart[KK + 1];
    __shared__ int tilek[MAXT];
    __shared__ unsigned short sorted[ROWS];

    const int tid = (int)threadIdx.x;
    const int lane = tid & 63;
    const int wave = tid >> 6;
    const int rowbase = (int)blockIdx.x * ROWS;

    if (tid < KK) { cnt[tid] = 0; rnk[tid] = 0; }
    if (tid < KK + 1)
        sedges[tid] = (tid == KK) ? 1000.0f : (float)tid / 10.0f;  // IEEE j/10
    for (int i = tid; i < KK * CSTRIDE / 4; i += 256)
        ((f32x4*)scst)[i] = ((const f32x4*)gcst)[i];
    __syncthreads();                                          // BAR1

    // ---- Phase 1: pack raw x (bf16) into LDS; arithmetic bucket ----
    int kq[2] = {-1, -1};
    #pragma unroll
    for (int i = 0; i < 2; ++i) {
        const int c    = tid + 256 * i;
        const int row  = c >> 1;
        const int half = c & 1;
        const float4* __restrict__ p =
            reinterpret_cast<const float4*>(x) + (size_t)blockIdx.x * (ROWS * DD / 4) + c * 4;
        float4 cc[4];
        #pragma unroll
        for (int j = 0; j < 4; ++j) cc[j] = p[j];

        const float e16 = __shfl(cc[0].x, lane + 1);  // odd lane's elem0 = x[16]
        const float t = cc[0].x;

        if (half == 0) {
            // candidate = ceil(t*10)-1, verified +-1 against exact edges
            int kc = (int)ceilf(t * 10.0f) - 1;
            kc = (kc < 0) ? 0 : ((kc > 19) ? 19 : kc);
            const float elo = sedges[kc];
            const float ehi = sedges[kc + 1];
            int kk = kc;
            if (t <= elo) kk = kc - 1;
            else if (t > ehi) kk = kc + 1;
            if (t > 2.0f) kk = (t <= 1000.0f) ? 20 : -1;
            if (t <= 0.0f) kk = -1;
            kq[i] = kk;
            if (kk >= 0) atomicAdd(&cnt[kk], 1);
            else out[rowbase + row] = 0.0f;
        }

        // even: x[1..16] (e16 via shfl); odd: x[17..31], pad 0
        const float* cf = (const float*)cc;
        const float f15 = half ? 0.0f : e16;
        unsigned* __restrict__ frow = fbf + row * FSTRIDE + half * 8;
        #pragma unroll
        for (int s = 0; s < 7; ++s)
            frow[s] = cvtpk(cf[2 * s + 1], cf[2 * s + 2]);
        frow[7] = cvtpk(cf[15], f15);
    }
    __syncthreads();                                          // BAR2

    // ---- Phase 2: wave-parallel scan + tile->k table + scatter ----
    if (tid < 64) {
        const int j = tid;
        const int c0 = (j < KK) ? cnt[j] : 0;
        const int t0 = (j < KK) ? ((c0 + 15) >> 4) : 0;
        int sc = c0, st = t0;
        #pragma unroll
        for (int off = 1; off < 32; off <<= 1) {
            const int vc = __shfl_up(sc, off);
            const int vt = __shfl_up(st, off);
            if (j >= off) { sc += vc; st += vt; }
        }
        if (j < KK) {
            sbase[j] = sc - c0;
            tstart[j] = st - t0;
            for (int t = st - t0; t < st; ++t) tilek[t] = j;   // tile -> bucket
        }
        if (j == KK) tstart[KK] = st;
    }
    __syncthreads();                                          // BAR3
    #pragma unroll
    for (int i = 0; i < 2; ++i) {
        const int c = tid + 256 * i;
        if (!(c & 1) && kq[i] >= 0) {
            const int rr = atomicAdd(&rnk[kq[i]], 1);
            sorted[sbase[kq[i]] + rr] = (unsigned short)(c >> 1);
        }
    }
    __syncthreads();                                          // BAR4

    // ---- Phase 3: software-pipelined MFMA tiles (bias as MFMA C-init) ----
    const int lrow = lane & 15;
    const int lgrp = lane >> 4;
    const int NT = tstart[KK];

    int tix = wave;
    int k0 = 0, cn0 = 0, rl0 = 0, R0 = 0;
    bf16x8 A0c = {}, A1c = {}, Bc = {};

    if (tix < NT) {
        k0 = __builtin_amdgcn_readfirstlane(tilek[tix]);
        cn0 = cnt[k0];
        rl0 = (tix - tstart[k0]) * 16 + lrow;
        R0 = sorted[sbase[k0] + min(rl0, cn0 - 1)];
        const unsigned* __restrict__ fr = fbf + R0 * FSTRIDE;
        const u32x2 wlo = *(const u32x2*)(fr + 2 * lgrp);
        const u32x2 whi = *(const u32x2*)(fr + 8 + 2 * lgrp);
        u32x4 bw; bw[0] = wlo[0]; bw[1] = wlo[1]; bw[2] = whi[0]; bw[3] = whi[1];
        Bc = __builtin_bit_cast(bf16x8, bw);
        A0c = A0tab[k0 * 64 + lane];
        A1c = A1tab[k0 * 64 + lane];
    }

    while (tix < NT) {
        const int nxt = tix + 4;
        const int pt = (nxt < NT) ? nxt : tix;
        const int k1 = __builtin_amdgcn_readfirstlane(tilek[pt]);
        const int cn1 = cnt[k1];
        const int rl1 = (pt - tstart[k1]) * 16 + lrow;
        const int R1 = sorted[sbase[k1] + min(rl1, cn1 - 1)];
        const unsigned* __restrict__ frn = fbf + R1 * FSTRIDE;
        const u32x2 nlo = *(const u32x2*)(frn + 2 * lgrp);
        const u32x2 nhi = *(const u32x2*)(frn + 8 + 2 * lgrp);
        u32x4 nw; nw[0] = nlo[0]; nw[1] = nlo[1]; nw[2] = nhi[0]; nw[3] = nhi[1];
        const bf16x8 Bn = __builtin_bit_cast(bf16x8, nw);
        const bf16x8 A0n = A0tab[k1 * 64 + lane];
        const bf16x8 A1n = A1tab[k1 * 64 + lane];

        const float* __restrict__ cp = scst + k0 * CSTRIDE;
        const f32x4 cb0 = *(const f32x4*)(cp + 4 * lgrp);
        const f32x4 cb1 = *(const f32x4*)(cp + 16 + 4 * lgrp);
        const f32x4 cw0 = *(const f32x4*)(cp + 32 + 4 * lgrp);
        const f32x4 cw1 = *(const f32x4*)(cp + 48 + 4 * lgrp);
        const float b2k = cp[64];

        // bias rides in as the MFMA C operand: h = b1' + A*B
        f32x4 acc0 = __builtin_amdgcn_mfma_f32_16x16x32_bf16(A0c, Bc, cb0, 0, 0, 0);
        f32x4 acc1 = __builtin_amdgcn_mfma_f32_16x16x32_bf16(A1c, Bc, cb1, 0, 0, 0);

        float S = 0.0f;
        #pragma unroll
        for (int rr = 0; rr < 4; ++rr) {
            const float q0 = fmaxf(acc0[rr], 0.1f * acc0[rr]);   // lrelu
            S = fmaf(q0, cw0[rr], S);
            const float q1 = fmaxf(acc1[rr], 0.1f * acc1[rr]);
            S = fmaf(q1, cw1[rr], S);
        }
        S += __shfl_xor(S, 16);
        S += __shfl_xor(S, 32);

        if (lgrp == 0 && rl0 < cn0) out[rowbase + R0] = S + b2k;

        k0 = k1; cn0 = cn1; rl0 = rl1; R0 = R1;
        A0c = A0n; A1c = A1n; Bc = Bn;
        tix = nxt;
    }
}

extern "C" void kernel_launch(void* const* d_in, const int* in_sizes, int n_in,
                              void* d_out, int out_size, void* d_ws, size_t ws_size,
                              hipStream_t stream) {
    const float* x  = (const float*)d_in[0];
    const float* a  = (const float*)d_in[1];
    const float* b  = (const float*)d_in[2];
    const float* W1 = (const float*)d_in[3];
    const float* b1 = (const float*)d_in[4];
    const float* W2 = (const float*)d_in[5];
    const float* b2 = (const float*)d_in[6];
    float* out = (float*)d_out;

    char* ws = (char*)d_ws;
    bf16x8* A0tab = (bf16x8*)ws;                       // 21*64*16B
    bf16x8* A1tab = A0tab + KK * 64;                   // 21*64*16B
    float* gcst  = (float*)(A1tab + KK * 64);          // 21*68*4B

    hipLaunchKernelGGL(prep_kernel, dim3(KK), dim3(64), 0, stream,
                       W1, b1, W2, b2, a, b, A0tab, A1tab, gcst);

    hipLaunchKernelGGL(fused_kernel, dim3(NN / ROWS), dim3(256), 0, stream,
                       x, A0tab, A1tab, gcst, out);
}